// Round 3
// baseline (945.254 us; speedup 1.0000x reference)
//
#include <hip/hip_runtime.h>
#include <stdint.h>

using u32 = unsigned int;
using u64 = unsigned long long;

constexpr int BATCH = 4;
constexpr int H0 = 1080, W0 = 1920;     // input
constexpr int HP = 539,  WP = 959;      // after conv1(3x3 VALID)+pool2
constexpr int H2 = 537,  W2 = 957;      // after conv2
constexpr int H3 = 535,  W3 = 955;      // after conv3
constexpr int N3 = H3 * W3;             // 510925
constexpr int TOT3 = BATCH * N3;        // 2043700
constexpr int KSEL = 1024;
constexpr int SORTCAP = 4096;
constexpr float SCORE_THR_C = 0.6f;
constexpr float IOU_THR_C = 0.5f;
constexpr float IMG_OFF = 100000.0f;

// pixel-group tiling (4 px wide per group)
constexpr int T1X = 480;   // conv1: group = 2 pooled px (4 conv px x 2 rows)
constexpr int T2X = 240;
constexpr int T3X = 239;
constexpr int NPG1 = BATCH * HP * T1X;   // 1,034,880
constexpr int NPG2 = BATCH * H2 * T2X;   //   515,520
constexpr int NPG3 = BATCH * H3 * T3X;   //   511,460

// ---------------- workspace layout (bytes) ----------------
constexpr size_t align256(size_t x) { return (x + 255) & ~(size_t)255; }
constexpr size_t oP1   = 0;
constexpr size_t sP1   = (size_t)BATCH * 10 * HP * WP * 4;     // 82.7 MB
constexpr size_t oC2   = align256(oP1 + sP1);
constexpr size_t sC2   = (size_t)BATCH * 16 * H2 * W2 * 4;     // 131.5 MB
constexpr size_t oCand = align256(oC2 + sC2);
constexpr size_t sCand = (size_t)TOT3 * 8;                     // 16.3 MB
constexpr size_t oSort = align256(oCand + sCand);
constexpr size_t oSel  = align256(oSort + (size_t)SORTCAP * 8);
constexpr size_t oBox  = align256(oSel + (size_t)KSEL * 8);
constexpr size_t oSup  = align256(oBox + (size_t)KSEL * 16);
constexpr size_t oKeep = align256(oSup + (size_t)KSEL * 16 * 8);
constexpr size_t oMisc = align256(oKeep + 16 * 8);
constexpr size_t MISC_WORDS = 16 + 2048;   // [0]=cand_count [1]=sel_count [2]=bstar [3]=keff ; +16: hist[2048]
constexpr size_t WS_NEEDED = oMisc + MISC_WORDS * 4;

__device__ __forceinline__ int keybin(u64 key) {
  u32 khi = (u32)(key >> 32);
  int d = (int)(khi - 0xC0800000u);   // scores in [0.5,1) land in [0, 0x800000)
  if (d < 0) d = 0;
  int bin = d >> 12;
  return bin > 2047 ? 2047 : bin;
}

// ---------------- conv1 + PReLU + 2x2 maxpool : 5 ch x 8 conv px / thread ----------------
// channel-half chosen by blockIdx bit 0 -> wave-uniform -> weights stay scalar loads
__global__ __launch_bounds__(256) void k_conv1(
    const float* __restrict__ x, const float* __restrict__ w1,
    const float* __restrict__ b1, const float* __restrict__ a1,
    float* __restrict__ P1) {
  int half = blockIdx.x & 1;
  int pg = (blockIdx.x >> 1) * 256 + threadIdx.x;
  if (pg >= NPG1) return;
  int tx = pg % T1X; int r = pg / T1X; int py = r % HP; int b = r / HP;
  int x0 = 4 * tx; if (x0 > 1914) x0 = 1914;   // clamp; overlap recompute is bit-identical
  int c_lo = half * 5;

  float acc[5][8];
  #pragma unroll
  for (int c = 0; c < 5; ++c) {
    float bb = b1[c_lo + c];
    #pragma unroll
    for (int o = 0; o < 8; ++o) acc[c][o] = bb;
  }
  const float* xb = x + (size_t)b * 3 * H0 * W0 + (size_t)(2 * py) * W0 + x0;
  #pragma unroll 1
  for (int ci = 0; ci < 3; ++ci) {
    const float* xp = xb + (size_t)ci * H0 * W0;
    float in[4][6];
    #pragma unroll
    for (int iy = 0; iy < 4; ++iy)
      #pragma unroll
      for (int ix = 0; ix < 6; ++ix)
        in[iy][ix] = xp[iy * W0 + ix];
    #pragma unroll
    for (int c = 0; c < 5; ++c) {
      const float* wc = w1 + ((c_lo + c) * 3 + ci) * 9;
      float w0v = wc[0], w1v = wc[1], w2v = wc[2], w3v = wc[3], w4v = wc[4],
            w5v = wc[5], w6v = wc[6], w7v = wc[7], w8v = wc[8];
      #pragma unroll
      for (int sr = 0; sr < 2; ++sr)
        #pragma unroll
        for (int sc = 0; sc < 4; ++sc) {
          float a = acc[c][sr * 4 + sc];
          a = fmaf(in[sr][sc],     w0v, a); a = fmaf(in[sr][sc+1],   w1v, a); a = fmaf(in[sr][sc+2],   w2v, a);
          a = fmaf(in[sr+1][sc],   w3v, a); a = fmaf(in[sr+1][sc+1], w4v, a); a = fmaf(in[sr+1][sc+2], w5v, a);
          a = fmaf(in[sr+2][sc],   w6v, a); a = fmaf(in[sr+2][sc+1], w7v, a); a = fmaf(in[sr+2][sc+2], w8v, a);
          acc[c][sr * 4 + sc] = a;
        }
    }
  }
  int P0 = x0 >> 1;
  size_t base = ((size_t)(b * 10 + c_lo) * HP + py) * WP + P0;
  #pragma unroll
  for (int c = 0; c < 5; ++c) {
    float al = a1[c_lo + c];
    float v[8];
    #pragma unroll
    for (int o = 0; o < 8; ++o) { float u = acc[c][o]; v[o] = u >= 0.0f ? u : al * u; }
    float m0 = fmaxf(fmaxf(v[0], v[1]), fmaxf(v[4], v[5]));
    float m1 = fmaxf(fmaxf(v[2], v[3]), fmaxf(v[6], v[7]));
    P1[base + (size_t)c * HP * WP]     = m0;
    P1[base + (size_t)c * HP * WP + 1] = m1;
  }
}

// ---------------- conv2 + PReLU : 8 ch x 4 px / thread (block-half channel split) ----------------
__global__ __launch_bounds__(256) void k_conv2(
    const float* __restrict__ P1, const float* __restrict__ w2,
    const float* __restrict__ b2, const float* __restrict__ a2,
    float* __restrict__ C2) {
  int half = blockIdx.x & 1;
  int pg = (blockIdx.x >> 1) * 256 + threadIdx.x;
  if (pg >= NPG2) return;
  int tx = pg % T2X; int r = pg / T2X; int y = r % H2; int b = r / H2;
  int x0 = 4 * tx; if (x0 > 953) x0 = 953;
  int c_lo = half * 8;

  float acc[8][4];
  #pragma unroll
  for (int c = 0; c < 8; ++c) {
    float bb = b2[c_lo + c];
    acc[c][0] = bb; acc[c][1] = bb; acc[c][2] = bb; acc[c][3] = bb;
  }
  #pragma unroll 1
  for (int ci = 0; ci < 10; ++ci) {
    const float* p = P1 + ((size_t)(b * 10 + ci) * HP + y) * WP + x0;
    float in[3][6];
    #pragma unroll
    for (int iy = 0; iy < 3; ++iy)
      #pragma unroll
      for (int ix = 0; ix < 6; ++ix)
        in[iy][ix] = p[iy * WP + ix];
    #pragma unroll
    for (int c = 0; c < 8; ++c) {
      const float* wc = w2 + ((c_lo + c) * 10 + ci) * 9;
      float w0v = wc[0], w1v = wc[1], w2v = wc[2], w3v = wc[3], w4v = wc[4],
            w5v = wc[5], w6v = wc[6], w7v = wc[7], w8v = wc[8];
      #pragma unroll
      for (int p4 = 0; p4 < 4; ++p4) {
        float a = acc[c][p4];
        a = fmaf(in[0][p4],   w0v, a); a = fmaf(in[0][p4+1], w1v, a); a = fmaf(in[0][p4+2], w2v, a);
        a = fmaf(in[1][p4],   w3v, a); a = fmaf(in[1][p4+1], w4v, a); a = fmaf(in[1][p4+2], w5v, a);
        a = fmaf(in[2][p4],   w6v, a); a = fmaf(in[2][p4+1], w7v, a); a = fmaf(in[2][p4+2], w8v, a);
        acc[c][p4] = a;
      }
    }
  }
  size_t base = ((size_t)(b * 16 + c_lo) * H2 + y) * W2 + x0;
  #pragma unroll
  for (int c = 0; c < 8; ++c) {
    float al = a2[c_lo + c];
    #pragma unroll
    for (int p4 = 0; p4 < 4; ++p4) {
      float v = acc[c][p4];
      v = v >= 0.0f ? v : al * v;
      C2[base + (size_t)c * H2 * W2 + p4] = v;
    }
  }
}

// ---------------- conv3 core (scalar 32-ch; used by k_emit only) ----------------
__device__ __forceinline__ void conv3_h(
    const float* __restrict__ C2, const float* __restrict__ w3,
    const float* __restrict__ b3, const float* __restrict__ a3,
    int b, int y, int x, float* h) {
  #pragma unroll
  for (int c = 0; c < 32; ++c) h[c] = b3[c];
  #pragma unroll 1
  for (int ci = 0; ci < 16; ++ci) {
    const float* p = C2 + ((size_t)(b * 16 + ci) * H2 + y) * W2 + x;
    float i0 = p[0],      i1 = p[1],      i2 = p[2];
    float i3 = p[W2],     i4 = p[W2+1],   i5 = p[W2+2];
    float i6 = p[2*W2],   i7 = p[2*W2+1], i8 = p[2*W2+2];
    const float* wp = w3 + ci * 9;
    #pragma unroll
    for (int c = 0; c < 32; ++c) {
      const float* wc = wp + c * 144;
      h[c] = fmaf(i0, wc[0], h[c]); h[c] = fmaf(i1, wc[1], h[c]);
      h[c] = fmaf(i2, wc[2], h[c]); h[c] = fmaf(i3, wc[3], h[c]);
      h[c] = fmaf(i4, wc[4], h[c]); h[c] = fmaf(i5, wc[5], h[c]);
      h[c] = fmaf(i6, wc[6], h[c]); h[c] = fmaf(i7, wc[7], h[c]);
      h[c] = fmaf(i8, wc[8], h[c]);
    }
  }
  #pragma unroll
  for (int c = 0; c < 32; ++c) h[c] = h[c] >= 0.0f ? h[c] : a3[c] * h[c];
}

// ---------------- conv3 + PReLU + softmax head + filter + fused histogram ----------------
// 16 ch x 4 px / thread; channel-half = tid bit 6 (wave-uniform). Head partials
// cross the half boundary via LDS, preserving exact sequential c=0..31 sum order.
__global__ __launch_bounds__(256) void k_conv3(
    const float* __restrict__ C2, const float* __restrict__ w3,
    const float* __restrict__ b3, const float* __restrict__ a3,
    const float* __restrict__ w41, const float* __restrict__ b41,
    u64* __restrict__ cands, u32* __restrict__ misc) {
  __shared__ u32 lh[2048];
  __shared__ float ex[2][8][66];   // [pairWave][p4*2+which][lane]
  int tid = threadIdx.x;
  for (int i = tid; i < 2048; i += 256) lh[i] = 0;
  __syncthreads();

  int lane = tid & 63;
  int half = (tid >> 6) & 1;
  int pw = tid >> 7;
  int pg = blockIdx.x * 128 + pw * 64 + lane;
  bool act = pg < NPG3;

  int y = 0, b = 0, xmin = 0, x0 = 0;
  float acc[16][4];
  if (act) {
    int tx = pg % T3X; int r = pg / T3X; y = r % H3; b = r / H3;
    xmin = 4 * tx; x0 = xmin > 951 ? 951 : xmin;
    int c_lo = half << 4;

    #pragma unroll
    for (int c = 0; c < 16; ++c) {
      float bb = b3[c_lo + c];
      acc[c][0] = bb; acc[c][1] = bb; acc[c][2] = bb; acc[c][3] = bb;
    }
    #pragma unroll 1
    for (int ci = 0; ci < 16; ++ci) {
      const float* p = C2 + ((size_t)(b * 16 + ci) * H2 + y) * W2 + x0;
      float in[3][6];
      #pragma unroll
      for (int iy = 0; iy < 3; ++iy)
        #pragma unroll
        for (int ix = 0; ix < 6; ++ix)
          in[iy][ix] = p[iy * W2 + ix];
      #pragma unroll
      for (int c = 0; c < 16; ++c) {
        const float* wc = w3 + ((c_lo + c) * 16 + ci) * 9;
        float w0v = wc[0], w1v = wc[1], w2v = wc[2], w3v = wc[3], w4v = wc[4],
              w5v = wc[5], w6v = wc[6], w7v = wc[7], w8v = wc[8];
        #pragma unroll
        for (int p4 = 0; p4 < 4; ++p4) {
          float a = acc[c][p4];
          a = fmaf(in[0][p4],   w0v, a); a = fmaf(in[0][p4+1], w1v, a); a = fmaf(in[0][p4+2], w2v, a);
          a = fmaf(in[1][p4],   w3v, a); a = fmaf(in[1][p4+1], w4v, a); a = fmaf(in[1][p4+2], w5v, a);
          a = fmaf(in[2][p4],   w6v, a); a = fmaf(in[2][p4+1], w7v, a); a = fmaf(in[2][p4+2], w8v, a);
          acc[c][p4] = a;
        }
      }
    }
    // PReLU (own channels)
    #pragma unroll
    for (int c = 0; c < 16; ++c) {
      float al = a3[c_lo + c];
      #pragma unroll
      for (int p4 = 0; p4 < 4; ++p4) {
        float v = acc[c][p4];
        acc[c][p4] = v >= 0.0f ? v : al * v;
      }
    }
    // head, first half: bias + channels 0..15 in exact order
    if (half == 0) {
      #pragma unroll
      for (int p4 = 0; p4 < 4; ++p4) {
        float s0 = b41[0], s1 = b41[1];
        #pragma unroll
        for (int c = 0; c < 16; ++c) {
          s0 = fmaf(acc[c][p4], w41[c],      s0);
          s1 = fmaf(acc[c][p4], w41[32 + c], s1);
        }
        ex[pw][p4 * 2][lane]     = s0;
        ex[pw][p4 * 2 + 1][lane] = s1;
      }
    }
  }
  __syncthreads();
  // head, second half: continue channels 16..31 in exact order; push candidates
  if (act && half == 1) {
    #pragma unroll
    for (int p4 = 0; p4 < 4; ++p4) {
      float l0 = ex[pw][p4 * 2][lane];
      float l1 = ex[pw][p4 * 2 + 1][lane];
      #pragma unroll
      for (int c = 0; c < 16; ++c) {
        l0 = fmaf(acc[c][p4], w41[16 + c], l0);
        l1 = fmaf(acc[c][p4], w41[48 + c], l1);
      }
      float prob = 1.0f / (1.0f + expf(l0 - l1));   // softmax[:,1] == sigmoid(l1-l0)
      int xe = x0 + p4;
      if (prob >= SCORE_THR_C && xe >= xmin) {
        u32 idx = (u32)(b * N3 + y * W3 + xe);
        u64 key = ((u64)(~__float_as_uint(prob)) << 32) | idx;
        atomicAdd(&lh[keybin(key)], 1u);
        u32 pos = atomicAdd(&misc[0], 1u);
        cands[pos] = key;
      }
    }
  }
  __syncthreads();
  for (int i = tid; i < 2048; i += 256) {
    u32 v = lh[i];
    if (v) atomicAdd(&misc[16 + i], v);
  }
}

// ---------------- top-k selection ----------------
__global__ __launch_bounds__(256) void k_scan(u32* __restrict__ misc) {
  __shared__ u32 lh[2048];
  int tid = threadIdx.x;
  const u32* hist = misc + 16;
  for (int t = tid; t < 2048; t += 256) lh[t] = hist[t];
  __syncthreads();
  if (tid == 0) {
    u32 total = misc[0]; if (total > (u32)TOT3) total = TOT3;
    u32 keff = total < (u32)KSEL ? total : (u32)KSEL;
    u32 run = 0; int bstar = 2047;
    for (int b = 0; b < 2048; ++b) {
      u32 hv = lh[b];
      if (run + hv >= keff) { bstar = b; break; }
      run += hv;
    }
    misc[2] = (u32)bstar;
    misc[3] = keff;
  }
}

__global__ __launch_bounds__(256) void k_compact(const u64* __restrict__ cands,
                                                u32* __restrict__ misc,
                                                u64* __restrict__ sortbuf) {
  u32 n = misc[0]; if (n > (u32)TOT3) n = TOT3;
  int bstar = (int)misc[2];
  u32 stride = gridDim.x * 256;
  for (u32 i = blockIdx.x * 256 + threadIdx.x; i < n; i += stride) {
    u64 key = cands[i];
    if (keybin(key) <= bstar) {
      u32 pos = atomicAdd(&misc[1], 1u);
      if (pos < (u32)SORTCAP) sortbuf[pos] = key;
    }
  }
}

// bitonic sort 4096 keys in LDS; emit sorted top-1024 keys + NMS boxes (with image offset)
__global__ __launch_bounds__(1024) void k_sort(const u64* __restrict__ sortbuf,
                                               const u32* __restrict__ misc,
                                               u64* __restrict__ selected,
                                               float4* __restrict__ boxarr) {
  __shared__ u64 s[SORTCAP];
  int tid = threadIdx.x;
  u32 nsel = misc[1]; if (nsel > (u32)SORTCAP) nsel = SORTCAP;
  for (int t = tid; t < SORTCAP; t += 1024) s[t] = (t < (int)nsel) ? sortbuf[t] : ~0ULL;
  for (unsigned k = 2; k <= (unsigned)SORTCAP; k <<= 1) {
    for (unsigned j = k >> 1; j > 0; j >>= 1) {
      __syncthreads();
      for (int t = tid; t < SORTCAP; t += 1024) {
        int ixj = t ^ (int)j;
        if (ixj > t) {
          u64 a = s[t], b = s[ixj];
          bool up = ((t & (int)k) == 0);
          if ((a > b) == up) { s[t] = b; s[ixj] = a; }
        }
      }
    }
  }
  __syncthreads();
  if (tid < KSEL) {
    u64 key = s[tid];
    selected[tid] = key;
    u32 idx = (u32)key;
    u32 b = idx / (u32)N3;
    u32 rem = idx - b * (u32)N3;
    u32 y = rem / (u32)W3;
    u32 x = rem - y * (u32)W3;
    float off = (float)b * IMG_OFF;
    float x1 = (float)(2 * (int)x + 1) + off;
    float y1 = (float)(2 * (int)y + 1) + off;
    boxarr[tid] = make_float4(x1, y1, x1 + 11.0f, y1 + 11.0f);
  }
}

// ---------------- NMS: suppression bitmask matrix ----------------
__global__ __launch_bounds__(256) void k_sup(const float4* __restrict__ boxarr,
                                             u64* __restrict__ sup) {
  __shared__ float4 lbox[KSEL];
  int tid = threadIdx.x;
  for (int t = tid; t < KSEL; t += 256) lbox[t] = boxarr[t];
  __syncthreads();
  int i = blockIdx.x * 16 + (tid >> 4);
  int w = tid & 15;
  float4 bi = lbox[i];
  float ai = (bi.z - bi.x) * (bi.w - bi.y);
  u64 m = 0;
  #pragma unroll 4
  for (int jj = 0; jj < 64; ++jj) {
    int j = (w << 6) + jj;
    float4 bj = lbox[j];
    float xx1 = fmaxf(bi.x, bj.x), yy1 = fmaxf(bi.y, bj.y);
    float xx2 = fminf(bi.z, bj.z), yy2 = fminf(bi.w, bj.w);
    float inter = fmaxf(xx2 - xx1, 0.0f) * fmaxf(yy2 - yy1, 0.0f);
    float aj = (bj.z - bj.x) * (bj.w - bj.y);
    float iou = inter / (ai + aj - inter);
    if (iou > IOU_THR_C && j > i) m |= (1ULL << jj);
  }
  sup[(size_t)i * 16 + w] = m;
}

// greedy NMS, survivor-skipping: iterate only kept boxes (ballot + ffs)
__global__ __launch_bounds__(256) void k_nms(const u64* __restrict__ sup,
                                             const u32* __restrict__ misc,
                                             u64* __restrict__ keep) {
  __shared__ u64 lsup[512 * 16];    // 64 KB
  int tid = threadIdx.x;
  int lane = tid & 63;
  int total = (int)misc[3];
  u64 kw = 0;
  if (tid < 16) {
    int nb = total - tid * 64;
    kw = nb >= 64 ? ~0ULL : (nb <= 0 ? 0ULL : ((1ULL << nb) - 1ULL));
  }
  u64 rem = kw;
  for (int chunk = 0; chunk < 2; ++chunk) {
    for (int t = tid; t < 512 * 16; t += 256) lsup[t] = sup[(size_t)chunk * 512 * 16 + t];
    __syncthreads();
    if (tid < 64) {
      int wlo = chunk * 8, whi = wlo + 8;
      while (true) {
        u64 bal = __ballot(lane >= wlo && lane < whi && rem != 0ULL);
        if (!bal) break;
        int w0 = __ffsll((u64)bal) - 1;
        u64 remw0 = __shfl(rem, w0);
        int bbit = __ffsll(remw0) - 1;
        int i = (w0 << 6) + bbit;
        u64 srow = (lane < 16) ? lsup[(i - (chunk << 9)) * 16 + lane] : 0ULL;
        if (lane == w0) rem &= ~(1ULL << bbit);
        kw &= ~srow;
        rem &= ~srow;
      }
    }
    __syncthreads();
  }
  if (tid < 16) keep[tid] = kw;
}

// ---------------- final emit: recompute pred head for kept rows ----------------
__global__ __launch_bounds__(256) void k_emit(
    const float* __restrict__ C2, const float* __restrict__ w3,
    const float* __restrict__ b3, const float* __restrict__ a3,
    const float* __restrict__ w42, const float* __restrict__ b42,
    const u64* __restrict__ selected, const u64* __restrict__ keep,
    float* __restrict__ out) {
  int r = blockIdx.x * 256 + threadIdx.x;
  if (r >= KSEL) return;
  bool kb = (keep[r >> 6] >> (r & 63)) & 1ULL;
  if (!kb) {
    out[r*5+0] = 0.0f; out[r*5+1] = 0.0f; out[r*5+2] = 0.0f;
    out[r*5+3] = 0.0f; out[r*5+4] = 0.0f;
    return;
  }
  u64 key = selected[r];
  float score = __uint_as_float(~(u32)(key >> 32));
  u32 idx = (u32)key;
  int b = (int)(idx / (u32)N3);
  int rem = (int)(idx - (u32)b * (u32)N3);
  int y = rem / W3;
  int x = rem - y * W3;
  float h[32];
  conv3_h(C2, w3, b3, a3, b, y, x, h);
  float p0 = b42[0], p1 = b42[1], p2 = b42[2], p3 = b42[3];
  #pragma unroll
  for (int c = 0; c < 32; ++c) {
    p0 = fmaf(h[c], w42[c],      p0);
    p1 = fmaf(h[c], w42[32 + c], p1);
    p2 = fmaf(h[c], w42[64 + c], p2);
    p3 = fmaf(h[c], w42[96 + c], p3);
  }
  float x1 = (float)(2 * x + 1), y1f = (float)(2 * y + 1);
  float x2 = (float)(2 * x + 12), y2f = (float)(2 * y + 12);
  float bw = x2 - x1, bh = y2f - y1f;
  float rx1 = fmaf(p0, bw, x1), ry1 = fmaf(p1, bh, y1f);
  float rx2 = fmaf(p2, bw, x2), ry2 = fmaf(p3, bh, y2f);
  float rw = rx2 - rx1, rh = ry2 - ry1;
  float l = fmaxf(rw, rh);
  float ox1 = rx1 + 0.5f * rw - 0.5f * l;
  float oy1 = ry1 + 0.5f * rh - 0.5f * l;
  out[r*5+0] = ox1; out[r*5+1] = oy1;
  out[r*5+2] = ox1 + l; out[r*5+3] = oy1 + l;
  out[r*5+4] = score;
}

extern "C" void kernel_launch(void* const* d_in, const int* in_sizes, int n_in,
                              void* d_out, int out_size, void* d_ws, size_t ws_size,
                              hipStream_t stream) {
  if (ws_size < WS_NEEDED) return;
  const float* x   = (const float*)d_in[0];
  const float* w1  = (const float*)d_in[1];
  const float* b1  = (const float*)d_in[2];
  const float* a1  = (const float*)d_in[3];
  const float* w2  = (const float*)d_in[4];
  const float* b2  = (const float*)d_in[5];
  const float* a2  = (const float*)d_in[6];
  const float* w3  = (const float*)d_in[7];
  const float* b3  = (const float*)d_in[8];
  const float* a3  = (const float*)d_in[9];
  const float* w41 = (const float*)d_in[10];
  const float* b41 = (const float*)d_in[11];
  const float* w42 = (const float*)d_in[12];
  const float* b42 = (const float*)d_in[13];

  char* ws = (char*)d_ws;
  float*  P1       = (float*)(ws + oP1);
  float*  C2       = (float*)(ws + oC2);
  u64*    cands    = (u64*)(ws + oCand);
  u64*    sortbuf  = (u64*)(ws + oSort);
  u64*    selected = (u64*)(ws + oSel);
  float4* boxarr   = (float4*)(ws + oBox);
  u64*    sup      = (u64*)(ws + oSup);
  u64*    keep     = (u64*)(ws + oKeep);
  u32*    misc     = (u32*)(ws + oMisc);
  float*  out      = (float*)d_out;

  hipMemsetAsync(misc, 0, MISC_WORDS * 4, stream);
  k_conv1<<<2 * ((NPG1 + 255) / 256), 256, 0, stream>>>(x, w1, b1, a1, P1);
  k_conv2<<<2 * ((NPG2 + 255) / 256), 256, 0, stream>>>(P1, w2, b2, a2, C2);
  k_conv3<<<(NPG3 + 127) / 128, 256, 0, stream>>>(C2, w3, b3, a3, w41, b41, cands, misc);
  k_scan<<<1, 256, 0, stream>>>(misc);
  k_compact<<<512, 256, 0, stream>>>(cands, misc, sortbuf);
  k_sort<<<1, 1024, 0, stream>>>(sortbuf, misc, selected, boxarr);
  k_sup<<<64, 256, 0, stream>>>(boxarr, sup);
  k_nms<<<1, 256, 0, stream>>>(sup, misc, keep);
  k_emit<<<(KSEL + 255) / 256, 256, 0, stream>>>(C2, w3, b3, a3, w42, b42, selected, keep, out);
}

// Round 4
// 783.637 us; speedup vs baseline: 1.2062x; 1.2062x over previous
//
#include <hip/hip_runtime.h>
#include <stdint.h>

using u32 = unsigned int;
using u64 = unsigned long long;

constexpr int BATCH = 4;
constexpr int H0 = 1080, W0 = 1920;     // input
constexpr int HP = 539,  WP = 959;      // after conv1(3x3 VALID)+pool2
constexpr int H2 = 537,  W2 = 957;      // after conv2
constexpr int H3 = 535,  W3 = 955;      // after conv3
constexpr int N3 = H3 * W3;             // 510925
constexpr int TOT3 = BATCH * N3;        // 2043700
constexpr int KSEL = 1024;
constexpr int SORTCAP = 4096;
constexpr float SCORE_THR_C = 0.6f;
constexpr float IOU_THR_C = 0.5f;
constexpr float IMG_OFF = 100000.0f;

// conv1 tiling (R2 structure)
constexpr int T1X = 480;
constexpr int NPG1 = BATCH * HP * T1X;

// conv2 tile: 8 rows x 64 cols ; conv3 tile: 8 rows x 32 cols
constexpr int C2TY = 68, C2TX = 15;     // ceil(537/8), ceil(957/64)
constexpr int C3TY = 67, C3TX = 30;     // ceil(535/8), ceil(955/32)

// ---------------- workspace layout (bytes) ----------------
constexpr size_t align256(size_t x) { return (x + 255) & ~(size_t)255; }
constexpr size_t oP1   = 0;
constexpr size_t sP1   = (size_t)BATCH * 10 * HP * WP * 4;     // 82.7 MB
constexpr size_t oC2   = align256(oP1 + sP1);
constexpr size_t sC2   = (size_t)BATCH * 16 * H2 * W2 * 4;     // 131.5 MB
constexpr size_t oCand = align256(oC2 + sC2);
constexpr size_t sCand = (size_t)TOT3 * 8;                     // 16.3 MB
constexpr size_t oSort = align256(oCand + sCand);
constexpr size_t oSel  = align256(oSort + (size_t)SORTCAP * 8);
constexpr size_t oBox  = align256(oSel + (size_t)KSEL * 8);
constexpr size_t oSup  = align256(oBox + (size_t)KSEL * 16);
constexpr size_t oKeep = align256(oSup + (size_t)KSEL * 16 * 8);
constexpr size_t oMisc = align256(oKeep + 16 * 8);
constexpr size_t MISC_WORDS = 16 + 2048;   // [0]=cand_count [1]=sel_count [2]=bstar [3]=keff ; +16: hist[2048]
constexpr size_t WS_NEEDED = oMisc + MISC_WORDS * 4;

__device__ __forceinline__ int keybin(u64 key) {
  u32 khi = (u32)(key >> 32);
  int d = (int)(khi - 0xC0800000u);   // scores in [0.5,1) land in [0, 0x800000)
  if (d < 0) d = 0;
  int bin = d >> 12;
  return bin > 2047 ? 2047 : bin;
}

// ---------------- conv1 + PReLU + 2x2 maxpool : 10 ch x 8 conv px / thread (R2) ----------------
__global__ __launch_bounds__(256) void k_conv1(
    const float* __restrict__ x, const float* __restrict__ w1,
    const float* __restrict__ b1, const float* __restrict__ a1,
    float* __restrict__ P1) {
  int t = blockIdx.x * 256 + threadIdx.x;
  if (t >= NPG1) return;
  int tx = t % T1X; int r = t / T1X; int py = r % HP; int b = r / HP;
  int x0 = 4 * tx; if (x0 > 1914) x0 = 1914;   // clamp; overlap recompute is bit-identical

  float acc[10][8];
  #pragma unroll
  for (int c = 0; c < 10; ++c) {
    float bb = b1[c];
    #pragma unroll
    for (int o = 0; o < 8; ++o) acc[c][o] = bb;
  }
  const float* xb = x + (size_t)b * 3 * H0 * W0 + (size_t)(2 * py) * W0 + x0;
  #pragma unroll 1
  for (int ci = 0; ci < 3; ++ci) {
    const float* xp = xb + (size_t)ci * H0 * W0;
    float in[4][6];
    #pragma unroll
    for (int iy = 0; iy < 4; ++iy)
      #pragma unroll
      for (int ix = 0; ix < 6; ++ix)
        in[iy][ix] = xp[iy * W0 + ix];
    #pragma unroll
    for (int c = 0; c < 10; ++c) {
      const float* wc = w1 + (c * 3 + ci) * 9;
      float w0v = wc[0], w1v = wc[1], w2v = wc[2], w3v = wc[3], w4v = wc[4],
            w5v = wc[5], w6v = wc[6], w7v = wc[7], w8v = wc[8];
      #pragma unroll
      for (int sr = 0; sr < 2; ++sr)
        #pragma unroll
        for (int sc = 0; sc < 4; ++sc) {
          float a = acc[c][sr * 4 + sc];
          a = fmaf(in[sr][sc],     w0v, a); a = fmaf(in[sr][sc+1],   w1v, a); a = fmaf(in[sr][sc+2],   w2v, a);
          a = fmaf(in[sr+1][sc],   w3v, a); a = fmaf(in[sr+1][sc+1], w4v, a); a = fmaf(in[sr+1][sc+2], w5v, a);
          a = fmaf(in[sr+2][sc],   w6v, a); a = fmaf(in[sr+2][sc+1], w7v, a); a = fmaf(in[sr+2][sc+2], w8v, a);
          acc[c][sr * 4 + sc] = a;
        }
    }
  }
  int P0 = x0 >> 1;
  size_t base = ((size_t)(b * 10) * HP + py) * WP + P0;
  #pragma unroll
  for (int c = 0; c < 10; ++c) {
    float al = a1[c];
    float v[8];
    #pragma unroll
    for (int o = 0; o < 8; ++o) { float u = acc[c][o]; v[o] = u >= 0.0f ? u : al * u; }
    float m0 = fmaxf(fmaxf(v[0], v[1]), fmaxf(v[4], v[5]));
    float m1 = fmaxf(fmaxf(v[2], v[3]), fmaxf(v[6], v[7]));
    P1[base + (size_t)c * HP * WP]     = m0;
    P1[base + (size_t)c * HP * WP + 1] = m1;
  }
}

// ---------------- conv2 + PReLU : LDS-tiled, tile 8x64, 4 waves = 2 ch-halves x 2 px-halves ----------------
// LDS: 10 planes x 10 rows x 66 cols, row stride 67 words (bank-safe), 26.8 KB
__global__ __launch_bounds__(256) void k_conv2(
    const float* __restrict__ P1, const float* __restrict__ w2,
    const float* __restrict__ b2, const float* __restrict__ a2,
    float* __restrict__ C2) {
  __shared__ float sm[6700];
  int tid = threadIdx.x;
  int blk = blockIdx.x;
  int tx = blk % C2TX; int r1 = blk / C2TX; int ty = r1 % C2TY; int b = r1 / C2TY;
  int r0 = 8 * ty;  if (r0 > 529) r0 = 529;    // clamp; overlap stores idempotent
  int c0 = 64 * tx; if (c0 > 893) c0 = 893;

  // stage input tile
  const float* Pb = P1 + (size_t)b * 10 * HP * WP;
  for (int i = tid; i < 6600; i += 256) {
    int ci = i / 660; int rem = i - ci * 660; int row = rem / 66; int col = rem - row * 66;
    sm[ci * 670 + row * 67 + col] =
        Pb[(size_t)ci * HP * WP + (size_t)(r0 + row) * WP + (c0 + col)];
  }
  __syncthreads();

  int lane = tid & 63;
  int wv = __builtin_amdgcn_readfirstlane(tid >> 6);
  int c_lo  = (wv >> 1) * 8;        // channel half
  int gbase = (wv & 1) * 8;         // column half
  int rr = lane >> 3;               // row 0..7
  int gg = lane & 7;                // col-group 0..7 (within half)
  int g4 = 4 * (gbase + gg);        // col offset in tile

  float acc[8][4];
  #pragma unroll
  for (int c = 0; c < 8; ++c) {
    float bb = b2[c_lo + c];
    acc[c][0] = bb; acc[c][1] = bb; acc[c][2] = bb; acc[c][3] = bb;
  }
  #pragma unroll 1
  for (int ci = 0; ci < 10; ++ci) {
    const float* sp = sm + ci * 670 + rr * 67 + g4;
    float in[3][6];
    #pragma unroll
    for (int dy = 0; dy < 3; ++dy)
      #pragma unroll
      for (int dx = 0; dx < 6; ++dx)
        in[dy][dx] = sp[dy * 67 + dx];
    #pragma unroll
    for (int c = 0; c < 8; ++c) {
      const float* wc = w2 + ((c_lo + c) * 10 + ci) * 9;
      float w0v = wc[0], w1v = wc[1], w2v = wc[2], w3v = wc[3], w4v = wc[4],
            w5v = wc[5], w6v = wc[6], w7v = wc[7], w8v = wc[8];
      #pragma unroll
      for (int k = 0; k < 4; ++k) {
        float a = acc[c][k];
        a = fmaf(in[0][k],   w0v, a); a = fmaf(in[0][k+1], w1v, a); a = fmaf(in[0][k+2], w2v, a);
        a = fmaf(in[1][k],   w3v, a); a = fmaf(in[1][k+1], w4v, a); a = fmaf(in[1][k+2], w5v, a);
        a = fmaf(in[2][k],   w6v, a); a = fmaf(in[2][k+1], w7v, a); a = fmaf(in[2][k+2], w8v, a);
        acc[c][k] = a;
      }
    }
  }
  int gy = r0 + rr, gx = c0 + g4;
  #pragma unroll
  for (int c = 0; c < 8; ++c) {
    float al = a2[c_lo + c];
    size_t base = ((size_t)(b * 16 + c_lo + c) * H2 + gy) * W2 + gx;
    #pragma unroll
    for (int k = 0; k < 4; ++k) {
      float v = acc[c][k];
      C2[base + k] = v >= 0.0f ? v : al * v;
    }
  }
}

// ---------------- conv3 core (scalar 32-ch; used by k_emit only) ----------------
__device__ __forceinline__ void conv3_h(
    const float* __restrict__ C2, const float* __restrict__ w3,
    const float* __restrict__ b3, const float* __restrict__ a3,
    int b, int y, int x, float* h) {
  #pragma unroll
  for (int c = 0; c < 32; ++c) h[c] = b3[c];
  #pragma unroll 1
  for (int ci = 0; ci < 16; ++ci) {
    const float* p = C2 + ((size_t)(b * 16 + ci) * H2 + y) * W2 + x;
    float i0 = p[0],      i1 = p[1],      i2 = p[2];
    float i3 = p[W2],     i4 = p[W2+1],   i5 = p[W2+2];
    float i6 = p[2*W2],   i7 = p[2*W2+1], i8 = p[2*W2+2];
    const float* wp = w3 + ci * 9;
    #pragma unroll
    for (int c = 0; c < 32; ++c) {
      const float* wc = wp + c * 144;
      h[c] = fmaf(i0, wc[0], h[c]); h[c] = fmaf(i1, wc[1], h[c]);
      h[c] = fmaf(i2, wc[2], h[c]); h[c] = fmaf(i3, wc[3], h[c]);
      h[c] = fmaf(i4, wc[4], h[c]); h[c] = fmaf(i5, wc[5], h[c]);
      h[c] = fmaf(i6, wc[6], h[c]); h[c] = fmaf(i7, wc[7], h[c]);
      h[c] = fmaf(i8, wc[8], h[c]);
    }
  }
  #pragma unroll
  for (int c = 0; c < 32; ++c) h[c] = h[c] >= 0.0f ? h[c] : a3[c] * h[c];
}

// ---------------- conv3 + PReLU + head + filter : LDS-tiled, tile 8x32, 4 waves x 8 ch ----------------
// LDS union: phase A/B input tile 16x10x(35) = 5600 words; phase C/D h[32][256] = 8192 words (32 KB)
__global__ __launch_bounds__(256) void k_conv3(
    const float* __restrict__ C2, const float* __restrict__ w3,
    const float* __restrict__ b3, const float* __restrict__ a3,
    const float* __restrict__ w41, const float* __restrict__ b41,
    u64* __restrict__ cands, u32* __restrict__ misc) {
  __shared__ __align__(16) float sm[8192];
  int tid = threadIdx.x;
  int blk = blockIdx.x;
  int tx = blk % C3TX; int r1 = blk / C3TX; int ty = r1 % C3TY; int b = r1 / C3TY;
  int ymin = 8 * ty, xmin = 32 * tx;
  int r0 = ymin > 527 ? 527 : ymin;
  int c0 = xmin > 923 ? 923 : xmin;

  // phase A: stage 16 x 10 x 34 input tile (row stride 35 words)
  const float* Cb = C2 + (size_t)b * 16 * H2 * W2;
  for (int i = tid; i < 5440; i += 256) {
    int ci = i / 340; int rem = i - ci * 340; int row = rem / 34; int col = rem - row * 34;
    sm[ci * 350 + row * 35 + col] =
        Cb[(size_t)ci * H2 * W2 + (size_t)(r0 + row) * W2 + (c0 + col)];
  }
  __syncthreads();

  // phase B: conv + PReLU. wave w: channels 8w..8w+7, whole tile (64 px-groups)
  int lane = tid & 63;
  int wv = __builtin_amdgcn_readfirstlane(tid >> 6);
  int c_lo = wv * 8;
  int rr = lane >> 3;      // row 0..7
  int gg = lane & 7;       // col-group 0..7

  float acc[8][4];
  #pragma unroll
  for (int c = 0; c < 8; ++c) {
    float bb = b3[c_lo + c];
    acc[c][0] = bb; acc[c][1] = bb; acc[c][2] = bb; acc[c][3] = bb;
  }
  #pragma unroll 1
  for (int ci = 0; ci < 16; ++ci) {
    const float* sp = sm + ci * 350 + rr * 35 + 4 * gg;
    float in[3][6];
    #pragma unroll
    for (int dy = 0; dy < 3; ++dy)
      #pragma unroll
      for (int dx = 0; dx < 6; ++dx)
        in[dy][dx] = sp[dy * 35 + dx];
    #pragma unroll
    for (int c = 0; c < 8; ++c) {
      const float* wc = w3 + ((c_lo + c) * 16 + ci) * 9;
      float w0v = wc[0], w1v = wc[1], w2v = wc[2], w3v = wc[3], w4v = wc[4],
            w5v = wc[5], w6v = wc[6], w7v = wc[7], w8v = wc[8];
      #pragma unroll
      for (int k = 0; k < 4; ++k) {
        float a = acc[c][k];
        a = fmaf(in[0][k],   w0v, a); a = fmaf(in[0][k+1], w1v, a); a = fmaf(in[0][k+2], w2v, a);
        a = fmaf(in[1][k],   w3v, a); a = fmaf(in[1][k+1], w4v, a); a = fmaf(in[1][k+2], w5v, a);
        a = fmaf(in[2][k],   w6v, a); a = fmaf(in[2][k+1], w7v, a); a = fmaf(in[2][k+2], w8v, a);
        acc[c][k] = a;
      }
    }
  }
  #pragma unroll
  for (int c = 0; c < 8; ++c) {
    float al = a3[c_lo + c];
    #pragma unroll
    for (int k = 0; k < 4; ++k) {
      float v = acc[c][k];
      acc[c][k] = v >= 0.0f ? v : al * v;
    }
  }
  __syncthreads();   // input tile dead

  // phase C: h -> LDS  h[ch][px], px = rr*32 + 4*gg + k  (float4 write, 16B aligned)
  #pragma unroll
  for (int c = 0; c < 8; ++c) {
    int word = (c_lo + c) * 256 + rr * 32 + 4 * gg;
    *(float4*)&sm[word] = make_float4(acc[c][0], acc[c][1], acc[c][2], acc[c][3]);
  }
  __syncthreads();

  // phase D: head per pixel (exact sequential c=0..31 sum), filter + push
  int p = tid;
  float l0 = b41[0], l1 = b41[1];
  #pragma unroll
  for (int c = 0; c < 32; ++c) {
    float hv = sm[c * 256 + p];
    l0 = fmaf(hv, w41[c],      l0);
    l1 = fmaf(hv, w41[32 + c], l1);
  }
  float prob = 1.0f / (1.0f + expf(l0 - l1));   // softmax[:,1] == sigmoid(l1-l0)
  int gy = r0 + (p >> 5);
  int gx = c0 + (p & 31);
  if (prob >= SCORE_THR_C && gy >= ymin && gx >= xmin) {
    u32 idx = (u32)(b * N3 + gy * W3 + gx);
    u64 key = ((u64)(~__float_as_uint(prob)) << 32) | idx;
    u32 pos = atomicAdd(&misc[0], 1u);
    cands[pos] = key;
  }
}

// ---------------- top-k selection ----------------
__global__ __launch_bounds__(256) void k_hist(const u64* __restrict__ cands, u32* __restrict__ misc) {
  __shared__ u32 lh[2048];
  int tid = threadIdx.x;
  for (int t = tid; t < 2048; t += 256) lh[t] = 0;
  __syncthreads();
  u32 n = misc[0]; if (n > (u32)TOT3) n = TOT3;
  u32 stride = gridDim.x * 256;
  for (u32 i = blockIdx.x * 256 + tid; i < n; i += stride)
    atomicAdd(&lh[keybin(cands[i])], 1u);
  __syncthreads();
  u32* hist = misc + 16;
  for (int t = tid; t < 2048; t += 256) if (lh[t]) atomicAdd(&hist[t], lh[t]);
}

__global__ __launch_bounds__(256) void k_scan(u32* __restrict__ misc) {
  __shared__ u32 lh[2048];
  int tid = threadIdx.x;
  const u32* hist = misc + 16;
  for (int t = tid; t < 2048; t += 256) lh[t] = hist[t];
  __syncthreads();
  if (tid == 0) {
    u32 total = misc[0]; if (total > (u32)TOT3) total = TOT3;
    u32 keff = total < (u32)KSEL ? total : (u32)KSEL;
    u32 run = 0; int bstar = 2047;
    for (int b = 0; b < 2048; ++b) {
      u32 hv = lh[b];
      if (run + hv >= keff) { bstar = b; break; }
      run += hv;
    }
    misc[2] = (u32)bstar;
    misc[3] = keff;
  }
}

__global__ __launch_bounds__(256) void k_compact(const u64* __restrict__ cands,
                                                u32* __restrict__ misc,
                                                u64* __restrict__ sortbuf) {
  u32 n = misc[0]; if (n > (u32)TOT3) n = TOT3;
  int bstar = (int)misc[2];
  u32 stride = gridDim.x * 256;
  for (u32 i = blockIdx.x * 256 + threadIdx.x; i < n; i += stride) {
    u64 key = cands[i];
    if (keybin(key) <= bstar) {
      u32 pos = atomicAdd(&misc[1], 1u);
      if (pos < (u32)SORTCAP) sortbuf[pos] = key;
    }
  }
}

// bitonic sort 4096 keys in LDS; emit sorted top-1024 keys + NMS boxes (with image offset)
__global__ __launch_bounds__(1024) void k_sort(const u64* __restrict__ sortbuf,
                                               const u32* __restrict__ misc,
                                               u64* __restrict__ selected,
                                               float4* __restrict__ boxarr) {
  __shared__ u64 s[SORTCAP];
  int tid = threadIdx.x;
  u32 nsel = misc[1]; if (nsel > (u32)SORTCAP) nsel = SORTCAP;
  for (int t = tid; t < SORTCAP; t += 1024) s[t] = (t < (int)nsel) ? sortbuf[t] : ~0ULL;
  for (unsigned k = 2; k <= (unsigned)SORTCAP; k <<= 1) {
    for (unsigned j = k >> 1; j > 0; j >>= 1) {
      __syncthreads();
      for (int t = tid; t < SORTCAP; t += 1024) {
        int ixj = t ^ (int)j;
        if (ixj > t) {
          u64 a = s[t], b = s[ixj];
          bool up = ((t & (int)k) == 0);
          if ((a > b) == up) { s[t] = b; s[ixj] = a; }
        }
      }
    }
  }
  __syncthreads();
  if (tid < KSEL) {
    u64 key = s[tid];
    selected[tid] = key;
    u32 idx = (u32)key;
    u32 b = idx / (u32)N3;
    u32 rem = idx - b * (u32)N3;
    u32 y = rem / (u32)W3;
    u32 x = rem - y * (u32)W3;
    float off = (float)b * IMG_OFF;
    float x1 = (float)(2 * (int)x + 1) + off;
    float y1 = (float)(2 * (int)y + 1) + off;
    boxarr[tid] = make_float4(x1, y1, x1 + 11.0f, y1 + 11.0f);
  }
}

// ---------------- NMS: suppression bitmask matrix ----------------
__global__ __launch_bounds__(256) void k_sup(const float4* __restrict__ boxarr,
                                             u64* __restrict__ sup) {
  __shared__ float4 lbox[KSEL];
  int tid = threadIdx.x;
  for (int t = tid; t < KSEL; t += 256) lbox[t] = boxarr[t];
  __syncthreads();
  int i = blockIdx.x * 16 + (tid >> 4);
  int w = tid & 15;
  float4 bi = lbox[i];
  float ai = (bi.z - bi.x) * (bi.w - bi.y);
  u64 m = 0;
  #pragma unroll 4
  for (int jj = 0; jj < 64; ++jj) {
    int j = (w << 6) + jj;
    float4 bj = lbox[j];
    float xx1 = fmaxf(bi.x, bj.x), yy1 = fmaxf(bi.y, bj.y);
    float xx2 = fminf(bi.z, bj.z), yy2 = fminf(bi.w, bj.w);
    float inter = fmaxf(xx2 - xx1, 0.0f) * fmaxf(yy2 - yy1, 0.0f);
    float aj = (bj.z - bj.x) * (bj.w - bj.y);
    float iou = inter / (ai + aj - inter);
    if (iou > IOU_THR_C && j > i) m |= (1ULL << jj);
  }
  sup[(size_t)i * 16 + w] = m;
}

// greedy NMS, survivor-skipping: iterate only kept boxes (ballot + ffs)
__global__ __launch_bounds__(256) void k_nms(const u64* __restrict__ sup,
                                             const u32* __restrict__ misc,
                                             u64* __restrict__ keep) {
  __shared__ u64 lsup[512 * 16];    // 64 KB
  int tid = threadIdx.x;
  int lane = tid & 63;
  int total = (int)misc[3];
  u64 kw = 0;
  if (tid < 16) {
    int nb = total - tid * 64;
    kw = nb >= 64 ? ~0ULL : (nb <= 0 ? 0ULL : ((1ULL << nb) - 1ULL));
  }
  u64 rem = kw;
  for (int chunk = 0; chunk < 2; ++chunk) {
    for (int t = tid; t < 512 * 16; t += 256) lsup[t] = sup[(size_t)chunk * 512 * 16 + t];
    __syncthreads();
    if (tid < 64) {
      int wlo = chunk * 8, whi = wlo + 8;
      while (true) {
        u64 bal = __ballot(lane >= wlo && lane < whi && rem != 0ULL);
        if (!bal) break;
        int w0 = __ffsll((u64)bal) - 1;
        u64 remw0 = __shfl(rem, w0);
        int bbit = __ffsll(remw0) - 1;
        int i = (w0 << 6) + bbit;
        u64 srow = (lane < 16) ? lsup[(i - (chunk << 9)) * 16 + lane] : 0ULL;
        if (lane == w0) rem &= ~(1ULL << bbit);
        kw &= ~srow;
        rem &= ~srow;
      }
    }
    __syncthreads();
  }
  if (tid < 16) keep[tid] = kw;
}

// ---------------- final emit: recompute pred head for kept rows ----------------
__global__ __launch_bounds__(256) void k_emit(
    const float* __restrict__ C2, const float* __restrict__ w3,
    const float* __restrict__ b3, const float* __restrict__ a3,
    const float* __restrict__ w42, const float* __restrict__ b42,
    const u64* __restrict__ selected, const u64* __restrict__ keep,
    float* __restrict__ out) {
  int r = blockIdx.x * 256 + threadIdx.x;
  if (r >= KSEL) return;
  bool kb = (keep[r >> 6] >> (r & 63)) & 1ULL;
  if (!kb) {
    out[r*5+0] = 0.0f; out[r*5+1] = 0.0f; out[r*5+2] = 0.0f;
    out[r*5+3] = 0.0f; out[r*5+4] = 0.0f;
    return;
  }
  u64 key = selected[r];
  float score = __uint_as_float(~(u32)(key >> 32));
  u32 idx = (u32)key;
  int b = (int)(idx / (u32)N3);
  int rem = (int)(idx - (u32)b * (u32)N3);
  int y = rem / W3;
  int x = rem - y * W3;
  float h[32];
  conv3_h(C2, w3, b3, a3, b, y, x, h);
  float p0 = b42[0], p1 = b42[1], p2 = b42[2], p3 = b42[3];
  #pragma unroll
  for (int c = 0; c < 32; ++c) {
    p0 = fmaf(h[c], w42[c],      p0);
    p1 = fmaf(h[c], w42[32 + c], p1);
    p2 = fmaf(h[c], w42[64 + c], p2);
    p3 = fmaf(h[c], w42[96 + c], p3);
  }
  float x1 = (float)(2 * x + 1), y1f = (float)(2 * y + 1);
  float x2 = (float)(2 * x + 12), y2f = (float)(2 * y + 12);
  float bw = x2 - x1, bh = y2f - y1f;
  float rx1 = fmaf(p0, bw, x1), ry1 = fmaf(p1, bh, y1f);
  float rx2 = fmaf(p2, bw, x2), ry2 = fmaf(p3, bh, y2f);
  float rw = rx2 - rx1, rh = ry2 - ry1;
  float l = fmaxf(rw, rh);
  float ox1 = rx1 + 0.5f * rw - 0.5f * l;
  float oy1 = ry1 + 0.5f * rh - 0.5f * l;
  out[r*5+0] = ox1; out[r*5+1] = oy1;
  out[r*5+2] = ox1 + l; out[r*5+3] = oy1 + l;
  out[r*5+4] = score;
}

extern "C" void kernel_launch(void* const* d_in, const int* in_sizes, int n_in,
                              void* d_out, int out_size, void* d_ws, size_t ws_size,
                              hipStream_t stream) {
  if (ws_size < WS_NEEDED) return;
  const float* x   = (const float*)d_in[0];
  const float* w1  = (const float*)d_in[1];
  const float* b1  = (const float*)d_in[2];
  const float* a1  = (const float*)d_in[3];
  const float* w2  = (const float*)d_in[4];
  const float* b2  = (const float*)d_in[5];
  const float* a2  = (const float*)d_in[6];
  const float* w3  = (const float*)d_in[7];
  const float* b3  = (const float*)d_in[8];
  const float* a3  = (const float*)d_in[9];
  const float* w41 = (const float*)d_in[10];
  const float* b41 = (const float*)d_in[11];
  const float* w42 = (const float*)d_in[12];
  const float* b42 = (const float*)d_in[13];

  char* ws = (char*)d_ws;
  float*  P1       = (float*)(ws + oP1);
  float*  C2       = (float*)(ws + oC2);
  u64*    cands    = (u64*)(ws + oCand);
  u64*    sortbuf  = (u64*)(ws + oSort);
  u64*    selected = (u64*)(ws + oSel);
  float4* boxarr   = (float4*)(ws + oBox);
  u64*    sup      = (u64*)(ws + oSup);
  u64*    keep     = (u64*)(ws + oKeep);
  u32*    misc     = (u32*)(ws + oMisc);
  float*  out      = (float*)d_out;

  hipMemsetAsync(misc, 0, MISC_WORDS * 4, stream);
  k_conv1<<<(NPG1 + 255) / 256, 256, 0, stream>>>(x, w1, b1, a1, P1);
  k_conv2<<<C2TX * C2TY * BATCH, 256, 0, stream>>>(P1, w2, b2, a2, C2);
  k_conv3<<<C3TX * C3TY * BATCH, 256, 0, stream>>>(C2, w3, b3, a3, w41, b41, cands, misc);
  k_hist<<<512, 256, 0, stream>>>(cands, misc);
  k_scan<<<1, 256, 0, stream>>>(misc);
  k_compact<<<512, 256, 0, stream>>>(cands, misc, sortbuf);
  k_sort<<<1, 1024, 0, stream>>>(sortbuf, misc, selected, boxarr);
  k_sup<<<64, 256, 0, stream>>>(boxarr, sup);
  k_nms<<<1, 256, 0, stream>>>(sup, misc, keep);
  k_emit<<<(KSEL + 255) / 256, 256, 0, stream>>>(C2, w3, b3, a3, w42, b42, selected, keep, out);
}